// Round 1
// baseline (2667.931 us; speedup 1.0000x reference)
//
#include <hip/hip_runtime.h>
#include <math.h>

#define TPB 256

// All activations for one sequence live here. Padded strides (19/37/73) to
// avoid systematic LDS bank conflicts on column-strided accesses.
struct SM {
  float x[48][19];    // residual stream (E=18)
  float h[48][19];    // LN output
  float up[48][73];   // mLSTM up-proj (xm|z); sLSTM wx; FFN act
  float xc[48][37];   // mLSTM conv output; sLSTM ys
  float q[48][37];    // q; later attention output / normed output
  float k[48][37];    // k; later hst
  float v[48][37];    // v; sLSTM hc
  float ipre[2][48];
  float fpre[2][48];
  float lfc[2][48];
  float st_y[18], st_c[18], st_n[18], st_m[18];  // sLSTM scan state
  float raw[4][18];
};

__device__ __forceinline__ float fast_sigmoid(float x){ return 1.f/(1.f+__expf(-x)); }
__device__ __forceinline__ float fast_silu(float x){ return x/(1.f+__expf(-x)); }
__device__ __forceinline__ float log_sigmoid(float x){ return fminf(x,0.f) - log1pf(__expf(-fabsf(x))); }

// LayerNorm(x) * w  ->  h   (eps 1e-5, over 18)
__device__ __forceinline__ void ln_x_to_h(SM& sm, int tid, const float* __restrict__ w){
  if (tid < 48){
    const int s = tid;
    float mu = 0.f;
    #pragma unroll
    for (int d=0; d<18; ++d) mu += sm.x[s][d];
    mu *= (1.f/18.f);
    float var = 0.f;
    #pragma unroll
    for (int d=0; d<18; ++d){ float t = sm.x[s][d]-mu; var += t*t; }
    var *= (1.f/18.f);
    const float r = rsqrtf(var + 1e-5f);
    #pragma unroll
    for (int d=0; d<18; ++d) sm.h[s][d] = (sm.x[s][d]-mu)*r*w[d];
  }
  __syncthreads();
}

__device__ void mlstm_block(SM& sm, int tid,
    const float* __restrict__ lnw, const float* __restrict__ upw,
    const float* __restrict__ cw,  const float* __restrict__ cb,
    const float* __restrict__ qw,  const float* __restrict__ kw,
    const float* __restrict__ vw,  const float* __restrict__ igw,
    const float* __restrict__ igb, const float* __restrict__ fgw,
    const float* __restrict__ fgb, const float* __restrict__ skp,
    const float* __restrict__ onw, const float* __restrict__ dwn)
{
  ln_x_to_h(sm, tid, lnw);

  // up-projection: (48,18) @ (18,72)
  for (int i=tid; i<48*72; i+=TPB){
    const int s=i/72, o=i%72;
    float acc=0.f;
    #pragma unroll
    for (int d=0; d<18; ++d) acc += sm.h[s][d]*upw[d*72+o];
    sm.up[s][o]=acc;
  }
  __syncthreads();

  // causal depthwise conv (k=4) + bias + silu on xm = up[:, :36]
  for (int i=tid; i<48*36; i+=TPB){
    const int s=i/36, c=i%36;
    float acc = cb[c];
    #pragma unroll
    for (int j=0; j<4; ++j){ const int sp=s-3+j; if (sp>=0) acc += sm.up[sp][c]*cw[c*4+j]; }
    sm.xc[s][c] = fast_silu(acc);
  }
  __syncthreads();

  // headwise q,k (from xc), v (from xm): 9 groups of 4x4
  for (int i=tid; i<48*36; i+=TPB){
    const int s=i/36, c=i%36, n=c>>2, o=c&3;
    float aq=0.f, ak=0.f, av=0.f;
    #pragma unroll
    for (int d=0; d<4; ++d){
      const float xcv = sm.xc[s][n*4+d];
      const float xmv = sm.up[s][n*4+d];
      aq += xcv*qw[n*16+o*4+d];
      ak += xcv*kw[n*16+o*4+d];
      av += xmv*vw[n*16+o*4+d];
    }
    sm.q[s][c]=aq; sm.k[s][c]=ak; sm.v[s][c]=av;
  }
  __syncthreads();

  // i/f gate pre-activations: gin = [q|k|v] (108) -> per (head, s)
  if (tid < 192){
    const int which = tid/96;          // 0: input gate, 1: forget gate
    const int h = (tid/48)&1, s = tid%48;
    const float* w = (which ? fgw : igw) + h*108;
    float acc = which ? fgb[h] : igb[h];
    #pragma unroll
    for (int f=0; f<36; ++f) acc += sm.q[s][f]*w[f];
    #pragma unroll
    for (int f=0; f<36; ++f) acc += sm.k[s][f]*w[36+f];
    #pragma unroll
    for (int f=0; f<36; ++f) acc += sm.v[s][f]*w[72+f];
    if (which) sm.fpre[h][s]=acc; else sm.ipre[h][s]=acc;
  }
  __syncthreads();

  // cumsum of log-sigmoid(fpre) along s
  if (tid < 2){
    float run=0.f;
    for (int s=0; s<48; ++s){ run += log_sigmoid(sm.fpre[tid][s]); sm.lfc[tid][s]=run; }
  }
  __syncthreads();

  // Fused attention row: per (head,row) compute row-max of logD, then one pass
  // over t<=s doing qk, D, PV-accumulate in registers; normalize; write to q.
  // Safe to overwrite q in-place: each thread only reads its own q row slice.
  if (tid < 96){
    const int hh = tid/48, ss = tid%48;
    const float ls = sm.lfc[hh][ss];
    float m = -1e30f;
    for (int t=0; t<=ss; ++t){
      const float l = ls - sm.lfc[hh][t] + sm.ipre[hh][t];
      m = fmaxf(m, l);
    }
    float acc[18];
    #pragma unroll
    for (int d=0; d<18; ++d) acc[d]=0.f;
    float rowsum = 0.f;
    for (int t=0; t<=ss; ++t){
      const float l = ls - sm.lfc[hh][t] + sm.ipre[hh][t];
      float qk = 0.f;
      #pragma unroll
      for (int d=0; d<18; ++d) qk += sm.q[ss][hh*18+d]*sm.k[t][hh*18+d];
      const float cc = qk*0.23570226039551584f*__expf(l - m);  // * D
      rowsum += cc;
      #pragma unroll
      for (int d=0; d<18; ++d) acc[d] += cc*sm.v[t][hh*18+d];
    }
    const float nrm = fmaxf(fabsf(rowsum), __expf(-m));
    const float ninv = 1.f/(nrm + 1e-6f);
    #pragma unroll
    for (int d=0; d<18; ++d) sm.q[ss][hh*18+d] = acc[d]*ninv;
  }
  __syncthreads();

  // per-(head,row) LN over 18 (eps 1e-5) * onw, in place on q
  if (tid < 96){
    const int h = tid&1, s = tid>>1;
    float mu=0.f;
    #pragma unroll
    for (int d=0; d<18; ++d) mu += sm.q[s][h*18+d];
    mu *= (1.f/18.f);
    float var=0.f;
    #pragma unroll
    for (int d=0; d<18; ++d){ float t = sm.q[s][h*18+d]-mu; var += t*t; }
    var *= (1.f/18.f);
    const float r = rsqrtf(var + 1e-5f);
    #pragma unroll
    for (int d=0; d<18; ++d){ const int c=h*18+d; sm.q[s][c] = (sm.q[s][c]-mu)*r*onw[c]; }
  }
  __syncthreads();

  // hst = (hn + skip*xc) * silu(z)  -> k buffer
  for (int i=tid; i<48*36; i+=TPB){
    const int s=i/36, c=i%36;
    sm.k[s][c] = (sm.q[s][c] + skp[c]*sm.xc[s][c]) * fast_silu(sm.up[s][36+c]);
  }
  __syncthreads();

  // down-projection (36->18) + residual
  for (int i=tid; i<48*18; i+=TPB){
    const int s=i/18, e=i%18;
    float a=0.f;
    #pragma unroll
    for (int c=0; c<36; ++c) a += sm.k[s][c]*dwn[c*18+e];
    sm.x[s][e] += a;
  }
  __syncthreads();
}

__device__ void slstm_block(SM& sm, int tid,
    const float* __restrict__ lnw, const float* __restrict__ cw, const float* __restrict__ cb,
    const float* __restrict__ gw,  const float* __restrict__ rw, const float* __restrict__ gb,
    const float* __restrict__ gnw, const float* __restrict__ flnw,
    const float* __restrict__ fup, const float* __restrict__ fdw)
{
  ln_x_to_h(sm, tid, lnw);

  // causal conv (E=18 channels) + silu -> v[s][0..17]  (hc)
  for (int i=tid; i<48*18; i+=TPB){
    const int s=i/18, c=i%18;
    float acc = cb[c];
    #pragma unroll
    for (int j=0; j<4; ++j){ const int sp=s-3+j; if (sp>=0) acc += sm.h[sp][c]*cw[c*4+j]; }
    sm.v[s][c] = fast_silu(acc);
  }
  __syncthreads();

  // wx (+bias) for all steps: up[s][g*18+h*9+e]; gates 0,1 use hc; 2,3 use h
  for (int i=tid; i<48*72; i+=TPB){
    const int s=i/72, r=i%72, g=r/18, t2=r%18, h=t2/9, e=t2%9;
    const float* wv = gw + ((g*2+h)*9+e)*9;
    const float* inp = (g<2) ? sm.v[s] : sm.h[s];
    float acc = gb[(g*2+h)*9+e];
    #pragma unroll
    for (int d=0; d<9; ++d) acc += inp[h*9+d]*wv[d];
    sm.up[s][r]=acc;
  }
  if (tid < 18){ sm.st_y[tid]=0.f; sm.st_c[tid]=0.f; sm.st_n[tid]=0.f; sm.st_m[tid]=0.f; }
  __syncthreads();

  // recurrent scan over 48 steps
  for (int s=0; s<48; ++s){
    if (tid < 72){
      const int g=tid/18, t2=tid%18, h=t2/9, e=t2%9;
      float acc = sm.up[s][tid];
      #pragma unroll
      for (int d=0; d<9; ++d) acc += sm.st_y[h*9+d]*rw[((h*9+d)*4+g)*9+e];
      sm.raw[g][t2]=acc;
    }
    __syncthreads();
    if (tid < 18){
      const float i_=sm.raw[0][tid], f_=sm.raw[1][tid], z_=sm.raw[2][tid], o_=sm.raw[3][tid];
      const float lfm = sm.st_m[tid] + log_sigmoid(f_);
      const float mn  = fmaxf(i_, lfm);
      const float ig  = __expf(i_-mn), fg = __expf(lfm-mn);
      const float cn  = fg*sm.st_c[tid] + ig*tanhf(z_);
      const float n2  = fg*sm.st_n[tid] + ig;
      const float yn  = fast_sigmoid(o_)*cn/n2;
      sm.st_c[tid]=cn; sm.st_n[tid]=n2; sm.st_m[tid]=mn; sm.st_y[tid]=yn;
      sm.xc[s][tid]=yn;
    }
    __syncthreads();
  }

  // group norm over DHS=9 per (s,h) * gnw, residual into x
  if (tid < 96){
    const int s=tid>>1, h=tid&1;
    float mu=0.f;
    #pragma unroll
    for (int e=0; e<9; ++e) mu += sm.xc[s][h*9+e];
    mu *= (1.f/9.f);
    float var=0.f;
    #pragma unroll
    for (int e=0; e<9; ++e){ float t=sm.xc[s][h*9+e]-mu; var += t*t; }
    var *= (1.f/9.f);
    const float r = rsqrtf(var + 1e-5f);
    #pragma unroll
    for (int e=0; e<9; ++e) sm.x[s][h*9+e] += (sm.xc[s][h*9+e]-mu)*r*gnw[h*9+e];
  }
  __syncthreads();

  // FFN: LN -> h; act = gelu(u[:,:64]) * u[:,64:] -> up; down + residual
  ln_x_to_h(sm, tid, flnw);
  for (int i=tid; i<48*64; i+=TPB){
    const int s=i/64, f=i%64;
    float ug=0.f, uu=0.f;
    #pragma unroll
    for (int d=0; d<18; ++d){ const float hv=sm.h[s][d]; ug += hv*fup[d*128+f]; uu += hv*fup[d*128+64+f]; }
    const float ge = 0.5f*ug*(1.f + erff(ug*0.70710678118654752f));
    sm.up[s][f] = ge*uu;
  }
  __syncthreads();
  for (int i=tid; i<48*18; i+=TPB){
    const int s=i/18, e=i%18;
    float a=0.f;
    #pragma unroll
    for (int f=0; f<64; ++f) a += sm.up[s][f]*fdw[f*18+e];
    sm.x[s][e] += a;
  }
  __syncthreads();
}

extern "C" __global__ void __launch_bounds__(TPB, 3)
xlstm_kernel(const float* __restrict__ gx,
             const float* __restrict__ m_ln_w,  const float* __restrict__ m_up_w,
             const float* __restrict__ m_conv_w,const float* __restrict__ m_conv_b,
             const float* __restrict__ m_q_w,   const float* __restrict__ m_k_w,
             const float* __restrict__ m_v_w,   const float* __restrict__ m_ig_w,
             const float* __restrict__ m_ig_b,  const float* __restrict__ m_fg_w,
             const float* __restrict__ m_fg_b,  const float* __restrict__ m_skip,
             const float* __restrict__ m_on_w,  const float* __restrict__ m_down_w,
             const float* __restrict__ s_ln_w,  const float* __restrict__ s_conv_w,
             const float* __restrict__ s_conv_b,const float* __restrict__ s_gate_w,
             const float* __restrict__ s_rec_w, const float* __restrict__ s_bias,
             const float* __restrict__ s_gn_w,  const float* __restrict__ f_ln_w,
             const float* __restrict__ f_up_w,  const float* __restrict__ f_down_w,
             const float* __restrict__ post_ln_w, const float* __restrict__ dense_w,
             const float* __restrict__ dense_b, float* __restrict__ gout)
{
  __shared__ SM sm;
  const int tid = threadIdx.x;
  const int b = blockIdx.x;

  for (int i=tid; i<48*18; i+=TPB) sm.x[i/18][i%18] = gx[b*864 + i];
  __syncthreads();

  int mj = 0;
  for (int blk=0; blk<7; ++blk){
    if (blk == 1){
      slstm_block(sm, tid, s_ln_w, s_conv_w, s_conv_b, s_gate_w, s_rec_w, s_bias,
                  s_gn_w, f_ln_w, f_up_w, f_down_w);
    } else {
      mlstm_block(sm, tid,
        m_ln_w + mj*18,      m_up_w + mj*(18*72),
        m_conv_w + mj*(36*4),m_conv_b + mj*36,
        m_q_w + mj*144,      m_k_w + mj*144,   m_v_w + mj*144,
        m_ig_w + mj*216,     m_ig_b + mj*2,
        m_fg_w + mj*216,     m_fg_b + mj*2,
        m_skip + mj*36,      m_on_w + mj*36,   m_down_w + mj*(36*18));
      ++mj;
    }
  }

  // final: post-LN, dense (18->1), zero s<24
  if (tid < 48){
    const int s = tid;
    float mu=0.f;
    #pragma unroll
    for (int d=0; d<18; ++d) mu += sm.x[s][d];
    mu *= (1.f/18.f);
    float var=0.f;
    #pragma unroll
    for (int d=0; d<18; ++d){ float t=sm.x[s][d]-mu; var += t*t; }
    var *= (1.f/18.f);
    const float r = rsqrtf(var + 1e-5f);
    float acc = dense_b[0];
    #pragma unroll
    for (int d=0; d<18; ++d) acc += (sm.x[s][d]-mu)*r*post_ln_w[d]*dense_w[d];
    gout[b*48 + s] = (s < 24) ? 0.f : acc;
  }
}

extern "C" void kernel_launch(void* const* d_in, const int* in_sizes, int n_in,
                              void* d_out, int out_size, void* d_ws, size_t ws_size,
                              hipStream_t stream)
{
  const float* gx        = (const float*)d_in[0];
  const float* m_ln_w    = (const float*)d_in[1];
  const float* m_up_w    = (const float*)d_in[2];
  const float* m_conv_w  = (const float*)d_in[3];
  const float* m_conv_b  = (const float*)d_in[4];
  const float* m_q_w     = (const float*)d_in[5];
  const float* m_k_w     = (const float*)d_in[6];
  const float* m_v_w     = (const float*)d_in[7];
  const float* m_ig_w    = (const float*)d_in[8];
  const float* m_ig_b    = (const float*)d_in[9];
  const float* m_fg_w    = (const float*)d_in[10];
  const float* m_fg_b    = (const float*)d_in[11];
  const float* m_skip    = (const float*)d_in[12];
  const float* m_on_w    = (const float*)d_in[13];
  const float* m_down_w  = (const float*)d_in[14];
  const float* s_ln_w    = (const float*)d_in[15];
  const float* s_conv_w  = (const float*)d_in[16];
  const float* s_conv_b  = (const float*)d_in[17];
  const float* s_gate_w  = (const float*)d_in[18];
  const float* s_rec_w   = (const float*)d_in[19];
  const float* s_bias    = (const float*)d_in[20];
  const float* s_gn_w    = (const float*)d_in[21];
  const float* f_ln_w    = (const float*)d_in[22];
  const float* f_up_w    = (const float*)d_in[23];
  const float* f_down_w  = (const float*)d_in[24];
  const float* post_ln_w = (const float*)d_in[25];
  const float* dense_w   = (const float*)d_in[26];
  const float* dense_b   = (const float*)d_in[27];

  const int B = in_sizes[0] / (48*18);
  xlstm_kernel<<<B, TPB, 0, stream>>>(gx,
    m_ln_w, m_up_w, m_conv_w, m_conv_b, m_q_w, m_k_w, m_v_w,
    m_ig_w, m_ig_b, m_fg_w, m_fg_b, m_skip, m_on_w, m_down_w,
    s_ln_w, s_conv_w, s_conv_b, s_gate_w, s_rec_w, s_bias, s_gn_w,
    f_ln_w, f_up_w, f_down_w, post_ln_w, dense_w, dense_b,
    (float*)d_out);
}

// Round 2
// 1903.161 us; speedup vs baseline: 1.4018x; 1.4018x over previous
//
#include <hip/hip_runtime.h>
#include <math.h>

#define TPB 256

// ---- flat LDS layout (floats). total 13104 floats = 52416 B -> 3 blocks/CU
constexpr int O_X   = 0;            // x[48][18]                       (864)
constexpr int O_XM  = 864;          // mLSTM xm[48][36]                (1728)
constexpr int O_H   = 864 + 1728;   // h[48][18]                       (864)
constexpr int O_CM  = 864;          // attention C[48][49] overlays XM+H (2352<=2592)
constexpr int O_Z   = 3456;         // z[48][36]                       (1728)
constexpr int O_XC  = 3456 + 1728;  // xc[48][36]                      (1728)
constexpr int O_WX  = 3456;         // sLSTM wx[2][48][36] overlays Z+XC (3456)
constexpr int O_FFN = 3456;         // FFN act[48][64] overlays Z+XC   (3072)
constexpr int O_Q   = 6912;         // q[48][37]                       (1776)
constexpr int O_K   = 8688;         // k[48][37]                       (1776)
constexpr int O_V   = 10464;        // v[48][37]                       (1776)
constexpr int O_HC  = 10464;        // sLSTM hc[48][18] overlays V     (864)
constexpr int O_YS  = 10464 + 864;  // sLSTM ys[48][18]                (864)
constexpr int O_IPRE= 12240;        // [2][48]
constexpr int O_FPRE= 12336;
constexpr int O_LFC = 12432;
constexpr int O_MR  = 12528;
constexpr int O_ROW = 12720;        // rowsum [2][48]
constexpr int O_AB  = 12816;        // gate fold weights [2g][2h][2w][36] (288)
constexpr int LDS_FLOATS = 13104;

__device__ __forceinline__ float fast_sigmoid(float x){ return 1.f/(1.f+__expf(-x)); }
__device__ __forceinline__ float fast_silu(float x){ return x/(1.f+__expf(-x)); }
__device__ __forceinline__ float log_sigmoid(float x){ return fminf(x,0.f) - log1pf(__expf(-fabsf(x))); }

// LN(x)*w -> h  (48 rows, threads 0..47); threads 48+ do optional AB precompute
__device__ __forceinline__ void ln_rows(float* L, int tid, const float* __restrict__ w){
  if (tid < 48){
    const int s = tid;
    float mu = 0.f;
    #pragma unroll
    for (int d=0; d<18; ++d) mu += L[O_X+s*18+d];
    mu *= (1.f/18.f);
    float var = 0.f;
    #pragma unroll
    for (int d=0; d<18; ++d){ float t = L[O_X+s*18+d]-mu; var += t*t; }
    var *= (1.f/18.f);
    const float r = rsqrtf(var + 1e-5f);
    #pragma unroll
    for (int d=0; d<18; ++d) L[O_H+s*18+d] = (L[O_X+s*18+d]-mu)*r*w[d];
  }
}

__device__ void mlstm_block(float* L, int tid,
    const float* __restrict__ lnw, const float* __restrict__ upw,
    const float* __restrict__ cw,  const float* __restrict__ cb,
    const float* __restrict__ qw,  const float* __restrict__ kw,
    const float* __restrict__ vw,  const float* __restrict__ igw,
    const float* __restrict__ igb, const float* __restrict__ fgw,
    const float* __restrict__ fgb, const float* __restrict__ skp,
    const float* __restrict__ onw, const float* __restrict__ dwn)
{
  // P1: LN (48 threads) + AB gate-fold precompute (threads 48..255)
  ln_rows(L, tid, lnw);
  if (tid >= 48){
    for (int i = tid-48; i < 288; i += 208){
      const int g = i/144, rem = i%144, h = rem/72, w2 = (rem%72)/36, c = rem%36;
      const int n = c>>2, d = c&3;
      const float* gatew = (g ? fgw : igw) + h*108;
      float val = 0.f;
      if (w2 == 0){
        #pragma unroll
        for (int o=0;o<4;++o) val += qw[n*16+o*4+d]*gatew[n*4+o] + kw[n*16+o*4+d]*gatew[36+n*4+o];
      } else {
        #pragma unroll
        for (int o=0;o<4;++o) val += vw[n*16+o*4+d]*gatew[72+n*4+o];
      }
      L[O_AB + ((g*2+h)*2+w2)*36 + c] = val;
    }
  }
  __syncthreads();

  // P2: up-projection (48x18)@(18x72) -> xm | z.  thread = (o, 16-row chunk)
  if (tid < 216){
    const int o = tid%72, sg = tid/72;
    float w[18];
    #pragma unroll
    for (int d=0; d<18; ++d) w[d] = upw[d*72+o];
    for (int s=sg*16; s<sg*16+16; ++s){
      const float2* hp = reinterpret_cast<const float2*>(&L[O_H + s*18]);
      float acc = 0.f;
      #pragma unroll
      for (int d2=0; d2<9; ++d2){ float2 hv = hp[d2]; acc += hv.x*w[2*d2] + hv.y*w[2*d2+1]; }
      if (o < 36) L[O_XM + s*36 + o] = acc; else L[O_Z + s*36 + (o-36)] = acc;
    }
  }
  __syncthreads();

  // P3: causal depthwise conv(k=4)+bias+silu on xm -> xc
  for (int i=tid; i<48*36; i+=TPB){
    const int s=i/36, c=i%36;
    float acc = cb[c];
    #pragma unroll
    for (int j=0; j<4; ++j){ const int sp=s-3+j; if (sp>=0) acc += L[O_XM+sp*36+c]*cw[c*4+j]; }
    L[O_XC+s*36+c] = fast_silu(acc);
  }
  __syncthreads();

  // P4: qkv (all threads) + gates via AB fold (threads<192)
  for (int i=tid; i<48*36; i+=TPB){
    const int s=i/36, c=i%36, n=c>>2, o=c&3;
    const float4 xcv = *reinterpret_cast<const float4*>(&L[O_XC+s*36+n*4]);
    const float4 xmv = *reinterpret_cast<const float4*>(&L[O_XM+s*36+n*4]);
    float aq = xcv.x*qw[n*16+o*4+0] + xcv.y*qw[n*16+o*4+1] + xcv.z*qw[n*16+o*4+2] + xcv.w*qw[n*16+o*4+3];
    float ak = xcv.x*kw[n*16+o*4+0] + xcv.y*kw[n*16+o*4+1] + xcv.z*kw[n*16+o*4+2] + xcv.w*kw[n*16+o*4+3];
    float av = xmv.x*vw[n*16+o*4+0] + xmv.y*vw[n*16+o*4+1] + xmv.z*vw[n*16+o*4+2] + xmv.w*vw[n*16+o*4+3];
    L[O_Q+s*37+c]=aq; L[O_K+s*37+c]=ak; L[O_V+s*37+c]=av;
  }
  if (tid < 192){
    const int g = tid/96, h = (tid/48)&1, s = tid%48;
    const float4* xcr = reinterpret_cast<const float4*>(&L[O_XC+s*36]);
    const float4* xmr = reinterpret_cast<const float4*>(&L[O_XM+s*36]);
    const float4* Ar  = reinterpret_cast<const float4*>(&L[O_AB + ((g*2+h)*2+0)*36]);
    const float4* Br  = reinterpret_cast<const float4*>(&L[O_AB + ((g*2+h)*2+1)*36]);
    float acc = g ? fgb[h] : igb[h];
    #pragma unroll
    for (int c4=0;c4<9;++c4){
      float4 a = xcr[c4], wa = Ar[c4];
      acc += a.x*wa.x + a.y*wa.y + a.z*wa.z + a.w*wa.w;
      float4 b = xmr[c4], wb = Br[c4];
      acc += b.x*wb.x + b.y*wb.y + b.z*wb.z + b.w*wb.w;
    }
    if (g) L[O_FPRE+h*48+s]=acc; else L[O_IPRE+h*48+s]=acc;
  }
  __syncthreads();

  // P5: per-head wave prefix scans: lfc = cumsum(logsig(fpre)); mr = lfc + cummax(ipre-lfc)
  if (tid < 128){
    const int h = tid>>6, lane = tid&63;
    float ls = (lane<48) ? log_sigmoid(L[O_FPRE+h*48+lane]) : 0.f;
    #pragma unroll
    for (int off=1; off<64; off<<=1){ float t = __shfl_up(ls, off); if (lane>=off) ls += t; }
    if (lane<48) L[O_LFC+h*48+lane] = ls;
    float u = (lane<48) ? (L[O_IPRE+h*48+lane] - ls) : -1e30f;
    #pragma unroll
    for (int off=1; off<64; off<<=1){ float t = __shfl_up(u, off); if (lane>=off) u = fmaxf(u,t); }
    if (lane<48) L[O_MR+h*48+lane] = ls + u;
  }
  __syncthreads();

  // P6: attention per head: stage A (balanced C cells), stage B (PV + rowsum)
  for (int h=0; h<2; ++h){
    for (int i=tid; i<1176; i+=TPB){
      const int r=i/49, j=i%49;
      const int s = (j<=r) ? r : 47-r;
      const int t = (j<=r) ? j : j-r-1;
      const float l = L[O_LFC+h*48+s] - L[O_LFC+h*48+t] + L[O_IPRE+h*48+t];
      const int qb = O_Q+s*37+h*18, kb = O_K+t*37+h*18;
      float qk = 0.f;
      #pragma unroll
      for (int d=0; d<18; ++d) qk += L[qb+d]*L[kb+d];
      L[O_CM + s*49 + t] = qk * 0.23570226039551584f * __expf(l - L[O_MR+h*48+s]);
    }
    __syncthreads();
    for (int i=tid; i<48*19; i+=TPB){
      const int srow=i/19, d=i%19;
      const int cb = O_CM+srow*49;
      float acc = 0.f;
      if (d < 18){
        const int vb = O_V+h*18+d;
        for (int t=0; t<=srow; ++t) acc += L[cb+t]*L[vb+t*37];
        L[O_Q+srow*37+h*18+d] = acc;          // own-head q is dead after stage A
      } else {
        for (int t=0; t<=srow; ++t) acc += L[cb+t];
        L[O_ROW+h*48+srow] = acc;
      }
    }
    __syncthreads();
  }

  // P7: normalize + per-(head,row) LN * onw, in place on q
  if (tid < 96){
    const int h = tid&1, s = tid>>1;
    const float nrm = fmaxf(fabsf(L[O_ROW+h*48+s]), __expf(-L[O_MR+h*48+s]));
    const float ninv = 1.f/(nrm + 1e-6f);
    float a[18]; float mu=0.f;
    #pragma unroll
    for (int d=0; d<18; ++d){ a[d] = L[O_Q+s*37+h*18+d]*ninv; mu += a[d]; }
    mu *= (1.f/18.f);
    float var=0.f;
    #pragma unroll
    for (int d=0; d<18; ++d){ float t=a[d]-mu; var += t*t; }
    var *= (1.f/18.f);
    const float r = rsqrtf(var + 1e-5f);
    #pragma unroll
    for (int d=0; d<18; ++d) L[O_Q+s*37+h*18+d] = (a[d]-mu)*r*onw[h*18+d];
  }
  __syncthreads();

  // P8: hst = (hn + skip*xc) * silu(z) -> xc (in place)
  for (int i=tid; i<48*36; i+=TPB){
    const int s=i/36, c=i%36;
    L[O_XC+s*36+c] = (L[O_Q+s*37+c] + skp[c]*L[O_XC+s*36+c]) * fast_silu(L[O_Z+s*36+c]);
  }
  __syncthreads();

  // P9: down-projection (36->18) + residual.  thread = (e, 4-row chunk)
  if (tid < 216){
    const int e = tid%18, sg = tid/18;
    float w[36];
    #pragma unroll
    for (int c=0; c<36; ++c) w[c] = dwn[c*18+e];
    for (int s=sg*4; s<sg*4+4; ++s){
      const float4* xr = reinterpret_cast<const float4*>(&L[O_XC+s*36]);
      float acc = 0.f;
      #pragma unroll
      for (int c4=0; c4<9; ++c4){
        float4 v = xr[c4];
        acc += v.x*w[4*c4] + v.y*w[4*c4+1] + v.z*w[4*c4+2] + v.w*w[4*c4+3];
      }
      L[O_X+s*18+e] += acc;
    }
  }
  __syncthreads();
}

__device__ void slstm_block(float* L, int tid,
    const float* __restrict__ lnw, const float* __restrict__ cw, const float* __restrict__ cb,
    const float* __restrict__ gw,  const float* __restrict__ rw, const float* __restrict__ gb,
    const float* __restrict__ gnw, const float* __restrict__ flnw,
    const float* __restrict__ fup, const float* __restrict__ fdw)
{
  // S1: LN
  ln_rows(L, tid, lnw);
  __syncthreads();

  // S2: causal conv(E=18)+silu on h -> hc
  for (int i=tid; i<48*18; i+=TPB){
    const int s=i/18, c=i%18;
    float acc = cb[c];
    #pragma unroll
    for (int j=0; j<4; ++j){ const int sp=s-3+j; if (sp>=0) acc += L[O_H+sp*18+c]*cw[c*4+j]; }
    L[O_HC+s*18+c] = fast_silu(acc);
  }
  __syncthreads();

  // S3: wx (+bias): wx[h][s][g*9+e]; gates 0,1 from hc; 2,3 from h
  for (int i=tid; i<2*48*36; i+=TPB){
    const int h = i/1728, rem = i%1728, s = rem/36, ge = rem%36, g = ge/9, e = ge%9;
    const int base = (g<2) ? O_HC : O_H;
    const float* wv = gw + ((g*2+h)*9+e)*9;
    float acc = gb[(g*2+h)*9+e];
    #pragma unroll
    for (int d=0; d<9; ++d) acc += L[base + s*18 + h*9 + d]*wv[d];
    L[O_WX + (h*48+s)*36 + ge] = acc;
  }
  __syncthreads();

  // S4: recurrent scan — one wave per head, pure shuffles, no barriers inside
  if (tid < 128){
    const int h = tid>>6, lane = tid&63;
    const int g = lane/9, e = lane%9;   // valid for lane<36
    float rwreg[9];
    if (lane < 36){
      #pragma unroll
      for (int d=0; d<9; ++d) rwreg[d] = rw[((h*9+d)*4+g)*9+e];
    } else {
      #pragma unroll
      for (int d=0; d<9; ++d) rwreg[d] = 0.f;
    }
    float yS=0.f, cS=0.f, nS=0.f, mS=0.f;
    for (int s=0; s<48; ++s){
      float raw = (lane<36) ? L[O_WX + (h*48+s)*36 + lane] : 0.f;
      #pragma unroll
      for (int d=0; d<9; ++d){ float yd = __shfl(yS, d); raw += yd*rwreg[d]; }
      const float i_ = __shfl(raw, e);
      const float f_ = __shfl(raw, 9+e);
      const float z_ = __shfl(raw, 18+e);
      const float o_ = __shfl(raw, 27+e);
      const float lfm = mS + log_sigmoid(f_);
      const float mn  = fmaxf(i_, lfm);
      const float ig  = __expf(i_-mn), fg = __expf(lfm-mn);
      const float th  = 1.f - 2.f/(__expf(2.f*z_)+1.f);
      cS = fg*cS + ig*th;
      nS = fg*nS + ig;
      mS = mn;
      yS = fast_sigmoid(o_)*cS/nS;
      if (lane < 9) L[O_YS + s*18 + h*9 + lane] = yS;
    }
  }
  __syncthreads();

  // S5: group norm over 9 per (s,h) * gnw, residual into x
  if (tid < 96){
    const int s=tid>>1, h=tid&1;
    float mu=0.f;
    #pragma unroll
    for (int e=0; e<9; ++e) mu += L[O_YS+s*18+h*9+e];
    mu *= (1.f/9.f);
    float var=0.f;
    #pragma unroll
    for (int e=0; e<9; ++e){ float t=L[O_YS+s*18+h*9+e]-mu; var += t*t; }
    var *= (1.f/9.f);
    const float r = rsqrtf(var + 1e-5f);
    #pragma unroll
    for (int e=0; e<9; ++e) L[O_X+s*18+h*9+e] += (L[O_YS+s*18+h*9+e]-mu)*r*gnw[h*9+e];
  }
  __syncthreads();

  // S6: FFN LN
  ln_rows(L, tid, flnw);
  __syncthreads();

  // S7: FFN up: act = gelu(h@Wg) * (h@Wu).  thread = (f, 12-row chunk)
  {
    const int f = tid&63, sg = tid>>6;
    float wg[18], wu[18];
    #pragma unroll
    for (int d=0; d<18; ++d){ wg[d]=fup[d*128+f]; wu[d]=fup[d*128+64+f]; }
    for (int s=sg*12; s<sg*12+12; ++s){
      const float2* hp = reinterpret_cast<const float2*>(&L[O_H + s*18]);
      float ug=0.f, uu=0.f;
      #pragma unroll
      for (int d2=0; d2<9; ++d2){
        float2 hv = hp[d2];
        ug += hv.x*wg[2*d2] + hv.y*wg[2*d2+1];
        uu += hv.x*wu[2*d2] + hv.y*wu[2*d2+1];
      }
      const float ge = 0.5f*ug*(1.f + erff(ug*0.70710678118654752f));
      L[O_FFN + s*64 + f] = ge*uu;
    }
  }
  __syncthreads();

  // S8: FFN down (64->18) + residual.  thread = (e, 4-row chunk)
  if (tid < 216){
    const int e = tid%18, sg = tid/18;
    float w[64];
    #pragma unroll
    for (int c=0; c<64; ++c) w[c] = fdw[c*18+e];
    for (int s=sg*4; s<sg*4+4; ++s){
      const float4* fr = reinterpret_cast<const float4*>(&L[O_FFN+s*64]);
      float acc = 0.f;
      #pragma unroll
      for (int c4=0; c4<16; ++c4){
        float4 v = fr[c4];
        acc += v.x*w[4*c4] + v.y*w[4*c4+1] + v.z*w[4*c4+2] + v.w*w[4*c4+3];
      }
      L[O_X+s*18+e] += acc;
    }
  }
  __syncthreads();
}

extern "C" __global__ void __launch_bounds__(TPB, 3)
xlstm_kernel(const float* __restrict__ gx,
             const float* __restrict__ m_ln_w,  const float* __restrict__ m_up_w,
             const float* __restrict__ m_conv_w,const float* __restrict__ m_conv_b,
             const float* __restrict__ m_q_w,   const float* __restrict__ m_k_w,
             const float* __restrict__ m_v_w,   const float* __restrict__ m_ig_w,
             const float* __restrict__ m_ig_b,  const float* __restrict__ m_fg_w,
             const float* __restrict__ m_fg_b,  const float* __restrict__ m_skip,
             const float* __restrict__ m_on_w,  const float* __restrict__ m_down_w,
             const float* __restrict__ s_ln_w,  const float* __restrict__ s_conv_w,
             const float* __restrict__ s_conv_b,const float* __restrict__ s_gate_w,
             const float* __restrict__ s_rec_w, const float* __restrict__ s_bias,
             const float* __restrict__ s_gn_w,  const float* __restrict__ f_ln_w,
             const float* __restrict__ f_up_w,  const float* __restrict__ f_down_w,
             const float* __restrict__ post_ln_w, const float* __restrict__ dense_w,
             const float* __restrict__ dense_b, float* __restrict__ gout)
{
  __shared__ float L[LDS_FLOATS];
  const int tid = threadIdx.x;
  const int b = blockIdx.x;

  for (int i=tid; i<48*18; i+=TPB) L[O_X+i] = gx[b*864 + i];
  __syncthreads();

  int mj = 0;
  for (int blk=0; blk<7; ++blk){
    if (blk == 1){
      slstm_block(L, tid, s_ln_w, s_conv_w, s_conv_b, s_gate_w, s_rec_w, s_bias,
                  s_gn_w, f_ln_w, f_up_w, f_down_w);
    } else {
      mlstm_block(L, tid,
        m_ln_w + mj*18,       m_up_w + mj*(18*72),
        m_conv_w + mj*(36*4), m_conv_b + mj*36,
        m_q_w + mj*144,       m_k_w + mj*144,   m_v_w + mj*144,
        m_ig_w + mj*216,      m_ig_b + mj*2,
        m_fg_w + mj*216,      m_fg_b + mj*2,
        m_skip + mj*36,       m_on_w + mj*36,   m_down_w + mj*(36*18));
      ++mj;
    }
  }

  // final: post-LN, dense (18->1), zero s<24
  if (tid < 48){
    const int s = tid;
    float mu=0.f;
    #pragma unroll
    for (int d=0; d<18; ++d) mu += L[O_X+s*18+d];
    mu *= (1.f/18.f);
    float var=0.f;
    #pragma unroll
    for (int d=0; d<18; ++d){ float t=L[O_X+s*18+d]-mu; var += t*t; }
    var *= (1.f/18.f);
    const float r = rsqrtf(var + 1e-5f);
    float acc = dense_b[0];
    #pragma unroll
    for (int d=0; d<18; ++d) acc += (L[O_X+s*18+d]-mu)*r*post_ln_w[d]*dense_w[d];
    gout[b*48 + s] = (s < 24) ? 0.f : acc;
  }
}

extern "C" void kernel_launch(void* const* d_in, const int* in_sizes, int n_in,
                              void* d_out, int out_size, void* d_ws, size_t ws_size,
                              hipStream_t stream)
{
  const float* gx        = (const float*)d_in[0];
  const float* m_ln_w    = (const float*)d_in[1];
  const float* m_up_w    = (const float*)d_in[2];
  const float* m_conv_w  = (const float*)d_in[3];
  const float* m_conv_b  = (const float*)d_in[4];
  const float* m_q_w     = (const float*)d_in[5];
  const float* m_k_w     = (const float*)d_in[6];
  const float* m_v_w     = (const float*)d_in[7];
  const float* m_ig_w    = (const float*)d_in[8];
  const float* m_ig_b    = (const float*)d_in[9];
  const float* m_fg_w    = (const float*)d_in[10];
  const float* m_fg_b    = (const float*)d_in[11];
  const float* m_skip    = (const float*)d_in[12];
  const float* m_on_w    = (const float*)d_in[13];
  const float* m_down_w  = (const float*)d_in[14];
  const float* s_ln_w    = (const float*)d_in[15];
  const float* s_conv_w  = (const float*)d_in[16];
  const float* s_conv_b  = (const float*)d_in[17];
  const float* s_gate_w  = (const float*)d_in[18];
  const float* s_rec_w   = (const float*)d_in[19];
  const float* s_bias    = (const float*)d_in[20];
  const float* s_gn_w    = (const float*)d_in[21];
  const float* f_ln_w    = (const float*)d_in[22];
  const float* f_up_w    = (const float*)d_in[23];
  const float* f_down_w  = (const float*)d_in[24];
  const float* post_ln_w = (const float*)d_in[25];
  const float* dense_w   = (const float*)d_in[26];
  const float* dense_b   = (const float*)d_in[27];

  const int B = in_sizes[0] / (48*18);
  xlstm_kernel<<<B, TPB, 0, stream>>>(gx,
    m_ln_w, m_up_w, m_conv_w, m_conv_b, m_q_w, m_k_w, m_v_w,
    m_ig_w, m_ig_b, m_fg_w, m_fg_b, m_skip, m_on_w, m_down_w,
    s_ln_w, s_conv_w, s_conv_b, s_gate_w, s_rec_w, s_bias, s_gn_w,
    f_ln_w, f_up_w, f_down_w, post_ln_w, dense_w, dense_b,
    (float*)d_out);
}

// Round 3
// 1674.557 us; speedup vs baseline: 1.5932x; 1.1365x over previous
//
#include <hip/hip_runtime.h>
#include <math.h>

#define TPB 256

// ---- flat LDS layout (floats). total 13152 floats = 52608 B -> 3 blocks/CU
constexpr int O_X   = 0;            // x[48][18]                       (864)
constexpr int O_XM  = 864;          // mLSTM xm[48][36]                (1728)
constexpr int O_H   = 864 + 1728;   // h[48][18]                       (864)
constexpr int O_CM  = 864;          // attention C[48][49] overlays XM+H (2352<=2592)
constexpr int O_Z   = 3456;         // z[48][36]                       (1728)
constexpr int O_XC  = 3456 + 1728;  // xc[48][36]                      (1728)
constexpr int O_WX  = 3456;         // sLSTM wx[2][48][36] overlays Z+XC (3456)
constexpr int O_FFN = 3456;         // FFN act[48][64] overlays Z+XC   (3072)
constexpr int O_Q   = 6912;         // q[48][38] (stride 38: float2-aligned)
constexpr int O_K   = 6912 + 1824;  // k[48][38]
constexpr int O_V   = 6912 + 3648;  // v[48][38]
constexpr int O_HC  = O_V;          // sLSTM hc[48][18] overlays V     (864)
constexpr int O_YS  = O_V + 864;    // sLSTM ys[48][18]                (864)
constexpr int O_IPRE= 12384;        // [2][48]
constexpr int O_FPRE= 12480;
constexpr int O_LFC = 12576;
constexpr int O_MR  = 12672;
constexpr int O_ROW = 12768;        // rowsum [2][48]
constexpr int O_AB  = 12864;        // gate fold weights [2g][2h][2w][36] (288)
constexpr int LDS_FLOATS = 13152;

__device__ __forceinline__ float fast_sigmoid(float x){ return 1.f/(1.f+__expf(-x)); }
__device__ __forceinline__ float fast_silu(float x){ return x/(1.f+__expf(-x)); }
__device__ __forceinline__ float log_sigmoid(float x){ return fminf(x,0.f) - log1pf(__expf(-fabsf(x))); }

// LN(x)*w -> h  (48 rows, threads 0..47)
__device__ __forceinline__ void ln_rows(float* L, int tid, const float* __restrict__ w){
  if (tid < 48){
    const int s = tid;
    float mu = 0.f;
    #pragma unroll
    for (int d=0; d<18; ++d) mu += L[O_X+s*18+d];
    mu *= (1.f/18.f);
    float var = 0.f;
    #pragma unroll
    for (int d=0; d<18; ++d){ float t = L[O_X+s*18+d]-mu; var += t*t; }
    var *= (1.f/18.f);
    const float r = rsqrtf(var + 1e-5f);
    #pragma unroll
    for (int d=0; d<18; ++d) L[O_H+s*18+d] = (L[O_X+s*18+d]-mu)*r*w[d];
  }
}

__device__ void mlstm_block(float* L, int tid,
    const float* __restrict__ lnw, const float* __restrict__ upw,
    const float* __restrict__ cw,  const float* __restrict__ cb,
    const float* __restrict__ qw,  const float* __restrict__ kw,
    const float* __restrict__ vw,  const float* __restrict__ igw,
    const float* __restrict__ igb, const float* __restrict__ fgw,
    const float* __restrict__ fgb, const float* __restrict__ skp,
    const float* __restrict__ onw, const float* __restrict__ dwn)
{
  // P1: LN (48 threads) + AB gate-fold precompute (threads 48..255)
  ln_rows(L, tid, lnw);
  if (tid >= 48){
    for (int i = tid-48; i < 288; i += 208){
      const int g = i/144, rem = i%144, h = rem/72, w2 = (rem%72)/36, c = rem%36;
      const int n = c>>2, d = c&3;
      const float* gatew = (g ? fgw : igw) + h*108;
      float val = 0.f;
      if (w2 == 0){
        #pragma unroll
        for (int o=0;o<4;++o) val += qw[n*16+o*4+d]*gatew[n*4+o] + kw[n*16+o*4+d]*gatew[36+n*4+o];
      } else {
        #pragma unroll
        for (int o=0;o<4;++o) val += vw[n*16+o*4+d]*gatew[72+n*4+o];
      }
      L[O_AB + ((g*2+h)*2+w2)*36 + c] = val;
    }
  }
  __syncthreads();

  // P2: up-projection (48x18)@(18x72) -> xm | z.  thread = (o, 16-row chunk)
  if (tid < 216){
    const int o = tid%72, sg = tid/72;
    float w[18];
    #pragma unroll
    for (int d=0; d<18; ++d) w[d] = upw[d*72+o];
    for (int s=sg*16; s<sg*16+16; ++s){
      const float2* hp = reinterpret_cast<const float2*>(&L[O_H + s*18]);
      float acc = 0.f;
      #pragma unroll
      for (int d2=0; d2<9; ++d2){ float2 hv = hp[d2]; acc += hv.x*w[2*d2] + hv.y*w[2*d2+1]; }
      if (o < 36) L[O_XM + s*36 + o] = acc; else L[O_Z + s*36 + (o-36)] = acc;
    }
  }
  __syncthreads();

  // P3: causal depthwise conv(k=4)+bias+silu on xm -> xc
  for (int i=tid; i<48*36; i+=TPB){
    const int s=i/36, c=i%36;
    float acc = cb[c];
    #pragma unroll
    for (int j=0; j<4; ++j){ const int sp=s-3+j; if (sp>=0) acc += L[O_XM+sp*36+c]*cw[c*4+j]; }
    L[O_XC+s*36+c] = fast_silu(acc);
  }
  __syncthreads();

  // P4: qkv (all threads) + gates via AB fold (threads<192)
  for (int i=tid; i<48*36; i+=TPB){
    const int s=i/36, c=i%36, n=c>>2, o=c&3;
    const float4 xcv = *reinterpret_cast<const float4*>(&L[O_XC+s*36+n*4]);
    const float4 xmv = *reinterpret_cast<const float4*>(&L[O_XM+s*36+n*4]);
    float aq = xcv.x*qw[n*16+o*4+0] + xcv.y*qw[n*16+o*4+1] + xcv.z*qw[n*16+o*4+2] + xcv.w*qw[n*16+o*4+3];
    float ak = xcv.x*kw[n*16+o*4+0] + xcv.y*kw[n*16+o*4+1] + xcv.z*kw[n*16+o*4+2] + xcv.w*kw[n*16+o*4+3];
    float av = xmv.x*vw[n*16+o*4+0] + xmv.y*vw[n*16+o*4+1] + xmv.z*vw[n*16+o*4+2] + xmv.w*vw[n*16+o*4+3];
    L[O_Q+s*38+c]=aq; L[O_K+s*38+c]=ak; L[O_V+s*38+c]=av;
  }
  if (tid < 192){
    const int g = tid/96, h = (tid/48)&1, s = tid%48;
    const float4* xcr = reinterpret_cast<const float4*>(&L[O_XC+s*36]);
    const float4* xmr = reinterpret_cast<const float4*>(&L[O_XM+s*36]);
    const float4* Ar  = reinterpret_cast<const float4*>(&L[O_AB + ((g*2+h)*2+0)*36]);
    const float4* Br  = reinterpret_cast<const float4*>(&L[O_AB + ((g*2+h)*2+1)*36]);
    float acc = g ? fgb[h] : igb[h];
    #pragma unroll
    for (int c4=0;c4<9;++c4){
      float4 a = xcr[c4], wa = Ar[c4];
      acc += a.x*wa.x + a.y*wa.y + a.z*wa.z + a.w*wa.w;
      float4 b = xmr[c4], wb = Br[c4];
      acc += b.x*wb.x + b.y*wb.y + b.z*wb.z + b.w*wb.w;
    }
    if (g) L[O_FPRE+h*48+s]=acc; else L[O_IPRE+h*48+s]=acc;
  }
  __syncthreads();

  // P5: per-head wave prefix scans: lfc = cumsum(logsig(fpre)); mr = lfc + cummax(ipre-lfc)
  if (tid < 128){
    const int h = tid>>6, lane = tid&63;
    float ls = (lane<48) ? log_sigmoid(L[O_FPRE+h*48+lane]) : 0.f;
    #pragma unroll
    for (int off=1; off<64; off<<=1){ float t = __shfl_up(ls, off); if (lane>=off) ls += t; }
    if (lane<48) L[O_LFC+h*48+lane] = ls;
    float u = (lane<48) ? (L[O_IPRE+h*48+lane] - ls) : -1e30f;
    #pragma unroll
    for (int off=1; off<64; off<<=1){ float t = __shfl_up(u, off); if (lane>=off) u = fmaxf(u,t); }
    if (lane<48) L[O_MR+h*48+lane] = ls + u;
  }
  __syncthreads();

  // P6: attention per head: stage A (balanced C cells, float2 qk), stage B (PV d-pairs)
  for (int h=0; h<2; ++h){
    for (int i=tid; i<1176; i+=TPB){
      const int r=i/49, j=i%49;
      const int s = (j<=r) ? r : 47-r;
      const int t = (j<=r) ? j : j-r-1;
      const float l = L[O_LFC+h*48+s] - L[O_LFC+h*48+t] + L[O_IPRE+h*48+t];
      const float2* q2 = reinterpret_cast<const float2*>(&L[O_Q+s*38+h*18]);
      const float2* k2 = reinterpret_cast<const float2*>(&L[O_K+t*38+h*18]);
      float qk = 0.f;
      #pragma unroll
      for (int d=0; d<9; ++d){ float2 a=q2[d], b=k2[d]; qk += a.x*b.x + a.y*b.y; }
      L[O_CM + s*49 + t] = qk * 0.23570226039551584f * __expf(l - L[O_MR+h*48+s]);
    }
    __syncthreads();
    // PV + rowsum: task = (row, slot); slot<9 -> d-pair 2*slot, slot==9 -> rowsum
    for (int i=tid; i<480; i+=TPB){
      const int srow=i/10, slot=i%10;
      const int cb = O_CM+srow*49;
      if (slot < 9){
        const float2* v2 = reinterpret_cast<const float2*>(&L[O_V+h*18+2*slot]);
        float ax=0.f, ay=0.f;
        for (int t=0; t<=srow; ++t){
          const float cc = L[cb+t];
          const float2 v = v2[t*19];           // stride 38 floats = 19 float2
          ax += cc*v.x; ay += cc*v.y;
        }
        L[O_Q+srow*38+h*18+2*slot]   = ax;     // own-head q dead after stage A
        L[O_Q+srow*38+h*18+2*slot+1] = ay;
      } else {
        float acc = 0.f;
        for (int t=0; t<=srow; ++t) acc += L[cb+t];
        L[O_ROW+h*48+srow] = acc;
      }
    }
    __syncthreads();
  }

  // P7: normalize + per-(head,row) LN * onw, in place on q
  if (tid < 96){
    const int h = tid&1, s = tid>>1;
    const float nrm = fmaxf(fabsf(L[O_ROW+h*48+s]), __expf(-L[O_MR+h*48+s]));
    const float ninv = 1.f/(nrm + 1e-6f);
    float a[18]; float mu=0.f;
    #pragma unroll
    for (int d=0; d<18; ++d){ a[d] = L[O_Q+s*38+h*18+d]*ninv; mu += a[d]; }
    mu *= (1.f/18.f);
    float var=0.f;
    #pragma unroll
    for (int d=0; d<18; ++d){ float t=a[d]-mu; var += t*t; }
    var *= (1.f/18.f);
    const float r = rsqrtf(var + 1e-5f);
    #pragma unroll
    for (int d=0; d<18; ++d) L[O_Q+s*38+h*18+d] = (a[d]-mu)*r*onw[h*18+d];
  }
  __syncthreads();

  // P8: hst = (hn + skip*xc) * silu(z) -> xc (in place)
  for (int i=tid; i<48*36; i+=TPB){
    const int s=i/36, c=i%36;
    L[O_XC+s*36+c] = (L[O_Q+s*38+c] + skp[c]*L[O_XC+s*36+c]) * fast_silu(L[O_Z+s*36+c]);
  }
  __syncthreads();

  // P9: down-projection (36->18) + residual.  thread = (e, 4-row chunk)
  if (tid < 216){
    const int e = tid%18, sg = tid/18;
    float w[36];
    #pragma unroll
    for (int c=0; c<36; ++c) w[c] = dwn[c*18+e];
    for (int s=sg*4; s<sg*4+4; ++s){
      const float4* xr = reinterpret_cast<const float4*>(&L[O_XC+s*36]);
      float acc = 0.f;
      #pragma unroll
      for (int c4=0; c4<9; ++c4){
        float4 v = xr[c4];
        acc += v.x*w[4*c4] + v.y*w[4*c4+1] + v.z*w[4*c4+2] + v.w*w[4*c4+3];
      }
      L[O_X+s*18+e] += acc;
    }
  }
  __syncthreads();
}

__device__ void slstm_block(float* L, int tid,
    const float* __restrict__ lnw, const float* __restrict__ cw, const float* __restrict__ cb,
    const float* __restrict__ gw,  const float* __restrict__ rw, const float* __restrict__ gb,
    const float* __restrict__ gnw, const float* __restrict__ flnw,
    const float* __restrict__ fup, const float* __restrict__ fdw)
{
  // S1: LN
  ln_rows(L, tid, lnw);
  __syncthreads();

  // S2: causal conv(E=18)+silu on h -> hc
  for (int i=tid; i<48*18; i+=TPB){
    const int s=i/18, c=i%18;
    float acc = cb[c];
    #pragma unroll
    for (int j=0; j<4; ++j){ const int sp=s-3+j; if (sp>=0) acc += L[O_H+sp*18+c]*cw[c*4+j]; }
    L[O_HC+s*18+c] = fast_silu(acc);
  }
  __syncthreads();

  // S3: wx (+bias): wx[h][s][g*9+e]; gates 0,1 from hc; 2,3 from h
  for (int i=tid; i<2*48*36; i+=TPB){
    const int h = i/1728, rem = i%1728, s = rem/36, ge = rem%36, g = ge/9, e = ge%9;
    const int base = (g<2) ? O_HC : O_H;
    const float* wv = gw + ((g*2+h)*9+e)*9;
    float acc = gb[(g*2+h)*9+e];
    #pragma unroll
    for (int d=0; d<9; ++d) acc += L[base + s*18 + h*9 + d]*wv[d];
    L[O_WX + (h*48+s)*36 + ge] = acc;
  }
  __syncthreads();

  // S4: recurrent scan — one wave per head, pure shuffles, no barriers inside
  if (tid < 128){
    const int h = tid>>6, lane = tid&63;
    const int g = lane/9, e = lane%9;   // valid for lane<36
    float rwreg[9];
    if (lane < 36){
      #pragma unroll
      for (int d=0; d<9; ++d) rwreg[d] = rw[((h*9+d)*4+g)*9+e];
    } else {
      #pragma unroll
      for (int d=0; d<9; ++d) rwreg[d] = 0.f;
    }
    float yS=0.f, cS=0.f, nS=0.f, mS=0.f;
    for (int s=0; s<48; ++s){
      float raw = (lane<36) ? L[O_WX + (h*48+s)*36 + lane] : 0.f;
      #pragma unroll
      for (int d=0; d<9; ++d){ float yd = __shfl(yS, d); raw += yd*rwreg[d]; }
      const float i_ = __shfl(raw, e);
      const float f_ = __shfl(raw, 9+e);
      const float z_ = __shfl(raw, 18+e);
      const float o_ = __shfl(raw, 27+e);
      const float lfm = mS + log_sigmoid(f_);
      const float mn  = fmaxf(i_, lfm);
      const float ig  = __expf(i_-mn), fg = __expf(lfm-mn);
      const float th  = 1.f - 2.f/(__expf(2.f*z_)+1.f);
      cS = fg*cS + ig*th;
      nS = fg*nS + ig;
      mS = mn;
      yS = fast_sigmoid(o_)*cS/nS;
      if (lane < 9) L[O_YS + s*18 + h*9 + lane] = yS;
    }
  }
  __syncthreads();

  // S5: group norm over 9 per (s,h) * gnw, residual into x
  if (tid < 96){
    const int s=tid>>1, h=tid&1;
    float mu=0.f;
    #pragma unroll
    for (int e=0; e<9; ++e) mu += L[O_YS+s*18+h*9+e];
    mu *= (1.f/9.f);
    float var=0.f;
    #pragma unroll
    for (int e=0; e<9; ++e){ float t=L[O_YS+s*18+h*9+e]-mu; var += t*t; }
    var *= (1.f/9.f);
    const float r = rsqrtf(var + 1e-5f);
    #pragma unroll
    for (int e=0; e<9; ++e) L[O_X+s*18+h*9+e] += (L[O_YS+s*18+h*9+e]-mu)*r*gnw[h*9+e];
  }
  __syncthreads();

  // S6: FFN LN
  ln_rows(L, tid, flnw);
  __syncthreads();

  // S7: FFN up: act = gelu(h@Wg) * (h@Wu).  thread = (f, 12-row chunk)
  {
    const int f = tid&63, sg = tid>>6;
    float wg[18], wu[18];
    #pragma unroll
    for (int d=0; d<18; ++d){ wg[d]=fup[d*128+f]; wu[d]=fup[d*128+64+f]; }
    for (int s=sg*12; s<sg*12+12; ++s){
      const float2* hp = reinterpret_cast<const float2*>(&L[O_H + s*18]);
      float ug=0.f, uu=0.f;
      #pragma unroll
      for (int d2=0; d2<9; ++d2){
        float2 hv = hp[d2];
        ug += hv.x*wg[2*d2] + hv.y*wg[2*d2+1];
        uu += hv.x*wu[2*d2] + hv.y*wu[2*d2+1];
      }
      const float ge = 0.5f*ug*(1.f + erff(ug*0.70710678118654752f));
      L[O_FFN + s*64 + f] = ge*uu;
    }
  }
  __syncthreads();

  // S8: FFN down (64->18) + residual.  thread = (e, 4-row chunk)
  if (tid < 216){
    const int e = tid%18, sg = tid/18;
    float w[64];
    #pragma unroll
    for (int c=0; c<64; ++c) w[c] = fdw[c*18+e];
    for (int s=sg*4; s<sg*4+4; ++s){
      const float4* fr = reinterpret_cast<const float4*>(&L[O_FFN+s*64]);
      float acc = 0.f;
      #pragma unroll
      for (int c4=0; c4<16; ++c4){
        float4 v = fr[c4];
        acc += v.x*w[4*c4] + v.y*w[4*c4+1] + v.z*w[4*c4+2] + v.w*w[4*c4+3];
      }
      L[O_X+s*18+e] += acc;
    }
  }
  __syncthreads();
}

extern "C" __global__ void __launch_bounds__(TPB, 3)
xlstm_kernel(const float* __restrict__ gx,
             const float* __restrict__ m_ln_w,  const float* __restrict__ m_up_w,
             const float* __restrict__ m_conv_w,const float* __restrict__ m_conv_b,
             const float* __restrict__ m_q_w,   const float* __restrict__ m_k_w,
             const float* __restrict__ m_v_w,   const float* __restrict__ m_ig_w,
             const float* __restrict__ m_ig_b,  const float* __restrict__ m_fg_w,
             const float* __restrict__ m_fg_b,  const float* __restrict__ m_skip,
             const float* __restrict__ m_on_w,  const float* __restrict__ m_down_w,
             const float* __restrict__ s_ln_w,  const float* __restrict__ s_conv_w,
             const float* __restrict__ s_conv_b,const float* __restrict__ s_gate_w,
             const float* __restrict__ s_rec_w, const float* __restrict__ s_bias,
             const float* __restrict__ s_gn_w,  const float* __restrict__ f_ln_w,
             const float* __restrict__ f_up_w,  const float* __restrict__ f_down_w,
             const float* __restrict__ post_ln_w, const float* __restrict__ dense_w,
             const float* __restrict__ dense_b, float* __restrict__ gout)
{
  __shared__ float L[LDS_FLOATS];
  const int tid = threadIdx.x;
  const int b = blockIdx.x;

  for (int i=tid; i<48*18; i+=TPB) L[O_X+i] = gx[b*864 + i];
  __syncthreads();

  int mj = 0;
  for (int blk=0; blk<7; ++blk){
    if (blk == 1){
      slstm_block(L, tid, s_ln_w, s_conv_w, s_conv_b, s_gate_w, s_rec_w, s_bias,
                  s_gn_w, f_ln_w, f_up_w, f_down_w);
    } else {
      mlstm_block(L, tid,
        m_ln_w + mj*18,       m_up_w + mj*(18*72),
        m_conv_w + mj*(36*4), m_conv_b + mj*36,
        m_q_w + mj*144,       m_k_w + mj*144,   m_v_w + mj*144,
        m_ig_w + mj*216,      m_ig_b + mj*2,
        m_fg_w + mj*216,      m_fg_b + mj*2,
        m_skip + mj*36,       m_on_w + mj*36,   m_down_w + mj*(36*18));
      ++mj;
    }
  }

  // final: post-LN, dense (18->1), zero s<24
  if (tid < 48){
    const int s = tid;
    float mu=0.f;
    #pragma unroll
    for (int d=0; d<18; ++d) mu += L[O_X+s*18+d];
    mu *= (1.f/18.f);
    float var=0.f;
    #pragma unroll
    for (int d=0; d<18; ++d){ float t=L[O_X+s*18+d]-mu; var += t*t; }
    var *= (1.f/18.f);
    const float r = rsqrtf(var + 1e-5f);
    float acc = dense_b[0];
    #pragma unroll
    for (int d=0; d<18; ++d) acc += (L[O_X+s*18+d]-mu)*r*post_ln_w[d]*dense_w[d];
    gout[b*48 + s] = (s < 24) ? 0.f : acc;
  }
}

extern "C" void kernel_launch(void* const* d_in, const int* in_sizes, int n_in,
                              void* d_out, int out_size, void* d_ws, size_t ws_size,
                              hipStream_t stream)
{
  const float* gx        = (const float*)d_in[0];
  const float* m_ln_w    = (const float*)d_in[1];
  const float* m_up_w    = (const float*)d_in[2];
  const float* m_conv_w  = (const float*)d_in[3];
  const float* m_conv_b  = (const float*)d_in[4];
  const float* m_q_w     = (const float*)d_in[5];
  const float* m_k_w     = (const float*)d_in[6];
  const float* m_v_w     = (const float*)d_in[7];
  const float* m_ig_w    = (const float*)d_in[8];
  const float* m_ig_b    = (const float*)d_in[9];
  const float* m_fg_w    = (const float*)d_in[10];
  const float* m_fg_b    = (const float*)d_in[11];
  const float* m_skip    = (const float*)d_in[12];
  const float* m_on_w    = (const float*)d_in[13];
  const float* m_down_w  = (const float*)d_in[14];
  const float* s_ln_w    = (const float*)d_in[15];
  const float* s_conv_w  = (const float*)d_in[16];
  const float* s_conv_b  = (const float*)d_in[17];
  const float* s_gate_w  = (const float*)d_in[18];
  const float* s_rec_w   = (const float*)d_in[19];
  const float* s_bias    = (const float*)d_in[20];
  const float* s_gn_w    = (const float*)d_in[21];
  const float* f_ln_w    = (const float*)d_in[22];
  const float* f_up_w    = (const float*)d_in[23];
  const float* f_down_w  = (const float*)d_in[24];
  const float* post_ln_w = (const float*)d_in[25];
  const float* dense_w   = (const float*)d_in[26];
  const float* dense_b   = (const float*)d_in[27];

  const int B = in_sizes[0] / (48*18);
  xlstm_kernel<<<B, TPB, 0, stream>>>(gx,
    m_ln_w, m_up_w, m_conv_w, m_conv_b, m_q_w, m_k_w, m_v_w,
    m_ig_w, m_ig_b, m_fg_w, m_fg_b, m_skip, m_on_w, m_down_w,
    s_ln_w, s_conv_w, s_conv_b, s_gate_w, s_rec_w, s_bias, s_gn_w,
    f_ln_w, f_up_w, f_down_w, post_ln_w, dense_w, dense_b,
    (float*)d_out);
}